// Round 1
// baseline (12705.779 us; speedup 1.0000x reference)
//
#include <hip/hip_runtime.h>

// Accumulator record per node (padded to 64 floats = 256 B, 4 cache lines):
//   [0] = count, [1..15] = S1, [16..30] = S2, [31..45] = S3, [46..60] = S4, [61..63] pad
#define REC 64

__device__ __forceinline__ float leaky(float x) { return x >= 0.f ? x : 0.1f * x; }

__global__ __launch_bounds__(256) void edge_kernel(
    const float* __restrict__ x_t, const float* __restrict__ edge_attr,
    const int* __restrict__ edge_index,            // [2*E]: first E = src, next E = tgt
    const float* __restrict__ w1a, const float* __restrict__ b1a,
    const float* __restrict__ w2a, const float* __restrict__ b2a,
    float* __restrict__ acc, int E)
{
    __shared__ float sw1[225], sw2[225], sb1[15], sb2[15];
    for (int i = threadIdx.x; i < 225; i += 256) { sw1[i] = w1a[i]; sw2[i] = w2a[i]; }
    if (threadIdx.x < 15) { sb1[threadIdx.x] = b1a[threadIdx.x]; sb2[threadIdx.x] = b2a[threadIdx.x]; }
    __syncthreads();

    int e = blockIdx.x * 256 + threadIdx.x;
    if (e >= E) return;

    int src = edge_index[e];
    int tgt = edge_index[E + e];

    float in[15];
#pragma unroll
    for (int k = 0; k < 5; k++)  in[k]     = x_t[tgt * 5 + k];
#pragma unroll
    for (int k = 0; k < 10; k++) in[5 + k] = edge_attr[(size_t)e * 10 + k];

    float h[15];
#pragma unroll
    for (int j = 0; j < 15; j++) {
        float a = sb1[j];
#pragma unroll
        for (int i = 0; i < 15; i++) a = fmaf(in[i], sw1[i * 15 + j], a);
        h[j] = leaky(a);
    }

    float* rec = acc + (size_t)src * REC;
    atomicAdd(rec, 1.0f);
#pragma unroll
    for (int j = 0; j < 15; j++) {
        float y = sb2[j];
#pragma unroll
        for (int i = 0; i < 15; i++) y = fmaf(h[i], sw2[i * 15 + j], y);
        float y2 = y * y;
        atomicAdd(rec + 1 + j,  y);
        atomicAdd(rec + 16 + j, y2);
        atomicAdd(rec + 31 + j, y2 * y);
        atomicAdd(rec + 46 + j, y2 * y2);
    }
}

__global__ __launch_bounds__(256) void node_kernel(
    const float* __restrict__ x_s, const float* __restrict__ u,
    const int* __restrict__ batch_s,
    const float* __restrict__ w1b, const float* __restrict__ b1b,
    const float* __restrict__ w2b, const float* __restrict__ b2b,
    const float* __restrict__ acc, float* __restrict__ out, int N)
{
    __shared__ float sw1[810], sw2[100], sb1[10], sb2[10];
    for (int i = threadIdx.x; i < 810; i += 256) sw1[i] = w1b[i];
    for (int i = threadIdx.x; i < 100; i += 256) sw2[i] = w2b[i];
    if (threadIdx.x < 10) { sb1[threadIdx.x] = b1b[threadIdx.x]; sb2[threadIdx.x] = b2b[threadIdx.x]; }
    __syncthreads();

    int i = blockIdx.x * 256 + threadIdx.x;
    if (i >= N) return;

    const float* rec = acc + (size_t)i * REC;
    float c = rec[0];
    float inv = 1.0f / fmaxf(c, 1.0f);

    float h[81];
#pragma unroll
    for (int k = 0; k < 10; k++) h[k] = x_s[i * 10 + k];
    h[10] = c;

#pragma unroll
    for (int f = 0; f < 15; f++) {
        float m1 = rec[1 + f]  * inv;
        float m2 = rec[16 + f] * inv;
        float m3 = rec[31 + f] * inv;
        float m4 = rec[46 + f] * inv;
        float var = fmaxf(m2 - m1 * m1, 0.0f);
        float sd  = sqrtf(var + 1e-6f);
        float m1sq = m1 * m1;
        float c3 = m3 - 3.0f * m1 * m2 + 2.0f * m1sq * m1;
        float c4 = m4 - 4.0f * m1 * m3 + 6.0f * m1sq * m2 - 3.0f * m1sq * m1sq;
        float is = 1.0f / sd;
        float is2 = is * is;
        h[11 + f] = m1;
        h[26 + f] = sd;
        h[41 + f] = c3 * is2 * is;
        h[56 + f] = c4 * is2 * is2;
    }

    int b = batch_s[i];
#pragma unroll
    for (int k = 0; k < 10; k++) h[71 + k] = u[b * 10 + k];

    float o1[10];
#pragma unroll
    for (int k = 0; k < 10; k++) {
        float a = sb1[k];
#pragma unroll
        for (int j = 0; j < 81; j++) a = fmaf(h[j], sw1[j * 10 + k], a);
        o1[k] = leaky(a);
    }
#pragma unroll
    for (int k = 0; k < 10; k++) {
        float a = sb2[k];
#pragma unroll
        for (int j = 0; j < 10; j++) a = fmaf(o1[j], sw2[j * 10 + k], a);
        out[(size_t)i * 10 + k] = a;
    }
}

extern "C" void kernel_launch(void* const* d_in, const int* in_sizes, int n_in,
                              void* d_out, int out_size, void* d_ws, size_t ws_size,
                              hipStream_t stream)
{
    const float* x_s       = (const float*)d_in[0];
    const float* x_t       = (const float*)d_in[1];
    const float* edge_attr = (const float*)d_in[2];
    const float* u         = (const float*)d_in[3];
    const int*   edge_index= (const int*)d_in[4];
    const int*   batch_s   = (const int*)d_in[5];
    const float* w1a = (const float*)d_in[6];
    const float* b1a = (const float*)d_in[7];
    const float* w2a = (const float*)d_in[8];
    const float* b2a = (const float*)d_in[9];
    const float* w1b = (const float*)d_in[10];
    const float* b1b = (const float*)d_in[11];
    const float* w2b = (const float*)d_in[12];
    const float* b2b = (const float*)d_in[13];

    int N = in_sizes[0] / 10;      // N_S
    int E = in_sizes[2] / 10;      // from edge_attr [E,10]

    float* acc = (float*)d_ws;
    hipMemsetAsync(d_ws, 0, (size_t)N * REC * sizeof(float), stream);

    edge_kernel<<<(E + 255) / 256, 256, 0, stream>>>(
        x_t, edge_attr, edge_index, w1a, b1a, w2a, b2a, acc, E);

    node_kernel<<<(N + 255) / 256, 256, 0, stream>>>(
        x_s, u, batch_s, w1b, b1b, w2b, b2b, acc, (float*)d_out, N);
}

// Round 2
// 824.541 us; speedup vs baseline: 15.4095x; 15.4095x over previous
//
#include <hip/hip_runtime.h>

#define REC 64  // accumulator record: [0]=count, [1..15]=S1, [16..30]=S2, [31..45]=S3, [46..60]=S4

__device__ __forceinline__ float leaky(float x) { return x >= 0.f ? x : 0.1f * x; }

// ---------------- phase 1: histogram of src ----------------
__global__ __launch_bounds__(256) void hist_kernel(const int* __restrict__ edge_index,
                                                   int* __restrict__ hist, int E)
{
    int e = blockIdx.x * 256 + threadIdx.x;
    if (e < E) atomicAdd(&hist[edge_index[e]], 1);
}

// ---------------- phase 2: exclusive scan over N counters ----------------
__global__ __launch_bounds__(1024) void scan1_kernel(const int* __restrict__ hist,
                                                     int* __restrict__ offsets,
                                                     int* __restrict__ bsums, int N)
{
    __shared__ int wsum[16];
    int gid  = blockIdx.x * 1024 + threadIdx.x;
    int lane = threadIdx.x & 63, wid = threadIdx.x >> 6;
    int v = (gid < N) ? hist[gid] : 0;
    int inc = v;
#pragma unroll
    for (int d = 1; d < 64; d <<= 1) { int n = __shfl_up(inc, d); if (lane >= d) inc += n; }
    if (lane == 63) wsum[wid] = inc;
    __syncthreads();
    if (threadIdx.x < 16) {
        int t = wsum[threadIdx.x];
        int inc2 = t;
#pragma unroll
        for (int d = 1; d < 16; d <<= 1) { int n = __shfl_up(inc2, d); if ((int)threadIdx.x >= d) inc2 += n; }
        wsum[threadIdx.x] = inc2 - t;                  // exclusive wave offset
        if (threadIdx.x == 15) bsums[blockIdx.x] = inc2;  // block total
    }
    __syncthreads();
    if (gid < N) offsets[gid] = inc - v + wsum[wid];
}

__global__ __launch_bounds__(64) void scan2_kernel(int* __restrict__ bsums, int nb)
{
    int lane = threadIdx.x;
    int carry = 0;
    for (int base = 0; base < nb; base += 64) {
        int i = base + lane;
        int v = (i < nb) ? bsums[i] : 0;
        int inc = v;
#pragma unroll
        for (int d = 1; d < 64; d <<= 1) { int n = __shfl_up(inc, d); if (lane >= d) inc += n; }
        if (i < nb) bsums[i] = inc - v + carry;
        carry += __shfl(inc, 63);
    }
}

__global__ __launch_bounds__(1024) void scan3_kernel(int* __restrict__ offsets,
                                                     int* __restrict__ cursor,
                                                     const int* __restrict__ bsums, int N)
{
    int gid = blockIdx.x * 1024 + threadIdx.x;
    if (gid < N) {
        int o = offsets[gid] + bsums[blockIdx.x];
        offsets[gid] = o;
        cursor[gid]  = o;
    }
}

// ---------------- phase 3: edge MLP + scatter into sorted position ----------------
__global__ __launch_bounds__(256) void scatter_kernel(
    const float* __restrict__ x_t, const float* __restrict__ edge_attr,
    const int* __restrict__ edge_index,
    const float* __restrict__ w1a, const float* __restrict__ b1a,
    const float* __restrict__ w2a, const float* __restrict__ b2a,
    int* __restrict__ cursor, float* __restrict__ msg, int E)
{
    __shared__ float sw1[225], sw2[225], sb1[15], sb2[15];
    for (int i = threadIdx.x; i < 225; i += 256) { sw1[i] = w1a[i]; sw2[i] = w2a[i]; }
    if (threadIdx.x < 15) { sb1[threadIdx.x] = b1a[threadIdx.x]; sb2[threadIdx.x] = b2a[threadIdx.x]; }
    __syncthreads();

    int e = blockIdx.x * 256 + threadIdx.x;
    if (e >= E) return;

    int src = edge_index[e];
    int tgt = edge_index[E + e];

    float in[15];
#pragma unroll
    for (int k = 0; k < 5; k++)  in[k]     = x_t[tgt * 5 + k];
#pragma unroll
    for (int k = 0; k < 10; k++) in[5 + k] = edge_attr[(size_t)e * 10 + k];

    float h[15];
#pragma unroll
    for (int j = 0; j < 15; j++) {
        float a = sb1[j];
#pragma unroll
        for (int i = 0; i < 15; i++) a = fmaf(in[i], sw1[i * 15 + j], a);
        h[j] = leaky(a);
    }

    float y[16];
#pragma unroll
    for (int j = 0; j < 15; j++) {
        float a = sb2[j];
#pragma unroll
        for (int i = 0; i < 15; i++) a = fmaf(h[i], sw2[i * 15 + j], a);
        y[j] = a;
    }
    y[15] = 0.f;

    int pos = atomicAdd(&cursor[src], 1);
    float4* dst = (float4*)(msg + (size_t)pos * 16);
    dst[0] = make_float4(y[0],  y[1],  y[2],  y[3]);
    dst[1] = make_float4(y[4],  y[5],  y[6],  y[7]);
    dst[2] = make_float4(y[8],  y[9],  y[10], y[11]);
    dst[3] = make_float4(y[12], y[13], y[14], y[15]);
}

// ---------------- phase 4: segmented reduction, one wave per node ----------------
__global__ __launch_bounds__(256) void reduce_kernel(
    const float* __restrict__ msg, const int* __restrict__ offsets,
    const int* __restrict__ hist, float* __restrict__ acc, int N)
{
    int wave = (blockIdx.x * 256 + threadIdx.x) >> 6;
    int lane = threadIdx.x & 63;
    if (wave >= N) return;

    int start = offsets[wave];
    int cnt   = hist[wave];
    int f = lane & 15, sub = lane >> 4;

    float s1 = 0.f, s2 = 0.f, s3 = 0.f, s4 = 0.f;
    const float* base = msg + (size_t)start * 16 + f;
    for (int k = sub; k < cnt; k += 4) {
        float v = base[(size_t)k * 16];
        float v2 = v * v;
        s1 += v; s2 += v2; s3 += v2 * v; s4 += v2 * v2;
    }
#pragma unroll
    for (int d = 16; d < 64; d <<= 1) {
        s1 += __shfl_xor(s1, d); s2 += __shfl_xor(s2, d);
        s3 += __shfl_xor(s3, d); s4 += __shfl_xor(s4, d);
    }

    float* rec = acc + (size_t)wave * REC;
    if (lane < 15) {
        rec[1 + lane]  = s1;
        rec[16 + lane] = s2;
        rec[31 + lane] = s3;
        rec[46 + lane] = s4;
    } else if (lane == 15) {
        rec[0] = (float)cnt;
    }
}

// ---------------- phase 5: node stats + MLP ----------------
__global__ __launch_bounds__(256) void node_kernel(
    const float* __restrict__ x_s, const float* __restrict__ u,
    const int* __restrict__ batch_s,
    const float* __restrict__ w1b, const float* __restrict__ b1b,
    const float* __restrict__ w2b, const float* __restrict__ b2b,
    const float* __restrict__ acc, float* __restrict__ out, int N)
{
    __shared__ float sw1[810], sw2[100], sb1[10], sb2[10];
    for (int i = threadIdx.x; i < 810; i += 256) sw1[i] = w1b[i];
    for (int i = threadIdx.x; i < 100; i += 256) sw2[i] = w2b[i];
    if (threadIdx.x < 10) { sb1[threadIdx.x] = b1b[threadIdx.x]; sb2[threadIdx.x] = b2b[threadIdx.x]; }
    __syncthreads();

    int i = blockIdx.x * 256 + threadIdx.x;
    if (i >= N) return;

    const float* rec = acc + (size_t)i * REC;
    float c = rec[0];
    float inv = 1.0f / fmaxf(c, 1.0f);

    float h[81];
#pragma unroll
    for (int k = 0; k < 10; k++) h[k] = x_s[i * 10 + k];
    h[10] = c;

#pragma unroll
    for (int f = 0; f < 15; f++) {
        float m1 = rec[1 + f]  * inv;
        float m2 = rec[16 + f] * inv;
        float m3 = rec[31 + f] * inv;
        float m4 = rec[46 + f] * inv;
        float var = fmaxf(m2 - m1 * m1, 0.0f);
        float sd  = sqrtf(var + 1e-6f);
        float m1sq = m1 * m1;
        float c3 = m3 - 3.0f * m1 * m2 + 2.0f * m1sq * m1;
        float c4 = m4 - 4.0f * m1 * m3 + 6.0f * m1sq * m2 - 3.0f * m1sq * m1sq;
        float is = 1.0f / sd;
        float is2 = is * is;
        h[11 + f] = m1;
        h[26 + f] = sd;
        h[41 + f] = c3 * is2 * is;
        h[56 + f] = c4 * is2 * is2;
    }

    int b = batch_s[i];
#pragma unroll
    for (int k = 0; k < 10; k++) h[71 + k] = u[b * 10 + k];

    float o1[10];
#pragma unroll
    for (int k = 0; k < 10; k++) {
        float a = sb1[k];
#pragma unroll
        for (int j = 0; j < 81; j++) a = fmaf(h[j], sw1[j * 10 + k], a);
        o1[k] = leaky(a);
    }
#pragma unroll
    for (int k = 0; k < 10; k++) {
        float a = sb2[k];
#pragma unroll
        for (int j = 0; j < 10; j++) a = fmaf(o1[j], sw2[j * 10 + k], a);
        out[(size_t)i * 10 + k] = a;
    }
}

// ---------------- fallback (ws too small): round-1 atomic path ----------------
__global__ __launch_bounds__(256) void edge_atomic_kernel(
    const float* __restrict__ x_t, const float* __restrict__ edge_attr,
    const int* __restrict__ edge_index,
    const float* __restrict__ w1a, const float* __restrict__ b1a,
    const float* __restrict__ w2a, const float* __restrict__ b2a,
    float* __restrict__ acc, int E)
{
    __shared__ float sw1[225], sw2[225], sb1[15], sb2[15];
    for (int i = threadIdx.x; i < 225; i += 256) { sw1[i] = w1a[i]; sw2[i] = w2a[i]; }
    if (threadIdx.x < 15) { sb1[threadIdx.x] = b1a[threadIdx.x]; sb2[threadIdx.x] = b2a[threadIdx.x]; }
    __syncthreads();
    int e = blockIdx.x * 256 + threadIdx.x;
    if (e >= E) return;
    int src = edge_index[e], tgt = edge_index[E + e];
    float in[15];
#pragma unroll
    for (int k = 0; k < 5; k++)  in[k]     = x_t[tgt * 5 + k];
#pragma unroll
    for (int k = 0; k < 10; k++) in[5 + k] = edge_attr[(size_t)e * 10 + k];
    float h[15];
#pragma unroll
    for (int j = 0; j < 15; j++) {
        float a = sb1[j];
#pragma unroll
        for (int i = 0; i < 15; i++) a = fmaf(in[i], sw1[i * 15 + j], a);
        h[j] = leaky(a);
    }
    float* rec = acc + (size_t)src * REC;
    atomicAdd(rec, 1.0f);
#pragma unroll
    for (int j = 0; j < 15; j++) {
        float y = sb2[j];
#pragma unroll
        for (int i = 0; i < 15; i++) y = fmaf(h[i], sw2[i * 15 + j], y);
        float y2 = y * y;
        atomicAdd(rec + 1 + j,  y);
        atomicAdd(rec + 16 + j, y2);
        atomicAdd(rec + 31 + j, y2 * y);
        atomicAdd(rec + 46 + j, y2 * y2);
    }
}

extern "C" void kernel_launch(void* const* d_in, const int* in_sizes, int n_in,
                              void* d_out, int out_size, void* d_ws, size_t ws_size,
                              hipStream_t stream)
{
    const float* x_s       = (const float*)d_in[0];
    const float* x_t       = (const float*)d_in[1];
    const float* edge_attr = (const float*)d_in[2];
    const float* u         = (const float*)d_in[3];
    const int*   edge_index= (const int*)d_in[4];
    const int*   batch_s   = (const int*)d_in[5];
    const float* w1a = (const float*)d_in[6];
    const float* b1a = (const float*)d_in[7];
    const float* w2a = (const float*)d_in[8];
    const float* b2a = (const float*)d_in[9];
    const float* w1b = (const float*)d_in[10];
    const float* b1b = (const float*)d_in[11];
    const float* w2b = (const float*)d_in[12];
    const float* b2b = (const float*)d_in[13];

    int N = in_sizes[0] / 10;   // N_S
    int E = in_sizes[2] / 10;   // edge_attr [E,10]
    int nb = (N + 1023) / 1024;

    // workspace layout
    size_t int_words = (size_t)3 * N + 1024;            // hist, offsets, cursor, bsums
    int*   hist    = (int*)d_ws;
    int*   offsets = hist + N;
    int*   cursor  = offsets + N;
    int*   bsums   = cursor + N;
    float* acc     = (float*)((char*)d_ws + int_words * sizeof(int));
    float* msg     = acc + (size_t)N * REC;
    size_t need = int_words * sizeof(int) + (size_t)N * REC * sizeof(float)
                + (size_t)E * 16 * sizeof(float);

    if (ws_size < need) {
        // fallback: atomic path (needs only acc)
        hipMemsetAsync(d_ws, 0, (size_t)N * REC * sizeof(float), stream);
        float* acc0 = (float*)d_ws;
        edge_atomic_kernel<<<(E + 255) / 256, 256, 0, stream>>>(
            x_t, edge_attr, edge_index, w1a, b1a, w2a, b2a, acc0, E);
        node_kernel<<<(N + 255) / 256, 256, 0, stream>>>(
            x_s, u, batch_s, w1b, b1b, w2b, b2b, acc0, (float*)d_out, N);
        return;
    }

    hipMemsetAsync(hist, 0, (size_t)N * sizeof(int), stream);

    hist_kernel<<<(E + 255) / 256, 256, 0, stream>>>(edge_index, hist, E);
    scan1_kernel<<<nb, 1024, 0, stream>>>(hist, offsets, bsums, N);
    scan2_kernel<<<1, 64, 0, stream>>>(bsums, nb);
    scan3_kernel<<<nb, 1024, 0, stream>>>(offsets, cursor, bsums, N);
    scatter_kernel<<<(E + 255) / 256, 256, 0, stream>>>(
        x_t, edge_attr, edge_index, w1a, b1a, w2a, b2a, cursor, msg, E);
    reduce_kernel<<<(N * 64 + 255) / 256, 256, 0, stream>>>(msg, offsets, hist, acc, N);
    node_kernel<<<(N + 255) / 256, 256, 0, stream>>>(
        x_s, u, batch_s, w1b, b1b, w2b, b2b, acc, (float*)d_out, N);
}